// Round 1
// baseline (4486.718 us; speedup 1.0000x reference)
//
#include <hip/hip_runtime.h>
#include <stdint.h>

typedef __bf16 bf16x8 __attribute__((ext_vector_type(8)));
typedef float  f32x4  __attribute__((ext_vector_type(4)));

__device__ __forceinline__ uint16_t f2b(float f) {
  uint32_t u = __float_as_uint(f);
  return (uint16_t)((u + 0x7FFFu + ((u >> 16) & 1u)) >> 16);
}
__device__ __forceinline__ float b2f(uint16_t h) {
  return __uint_as_float(((uint32_t)h) << 16);
}
__device__ __forceinline__ uint4 pack8f(float4 a, float4 b) {
  uint4 r;
  r.x = (uint32_t)f2b(a.x) | ((uint32_t)f2b(a.y) << 16);
  r.y = (uint32_t)f2b(a.z) | ((uint32_t)f2b(a.w) << 16);
  r.z = (uint32_t)f2b(b.x) | ((uint32_t)f2b(b.y) << 16);
  r.w = (uint32_t)f2b(b.z) | ((uint32_t)f2b(b.w) << 16);
  return r;
}

// -------------------------------------------------------------------------
// Dtype detector: if W_proj is bf16-packed, low 16 bits of each u32 word are a
// plausible N(0,0.02) bf16 sample (~99.6% in (1e-4,0.5)); if fp32, low bits are
// mantissa noise (~5% pass). flag=1 -> bf16 buffers, flag=0 -> fp32 buffers.
__global__ void detect_kernel(const uint32_t* __restrict__ wproj, int* flag) {
  __shared__ int cnt;
  if (threadIdx.x == 0) cnt = 0;
  __syncthreads();
  int local = 0;
  for (int i = threadIdx.x; i < 1024; i += 256) {
    float v = __uint_as_float((wproj[i] & 0xFFFFu) << 16);
    float av = fabsf(v);
    if (av > 1e-4f && av < 0.5f) local++;
  }
  atomicAdd(&cnt, local);
  __syncthreads();
  if (threadIdx.x == 0) flag[0] = (cnt > 512) ? 1 : 0;
}

// Convert n elements (n % 2048 == 0) to canonical bf16. One thread = 8 elems.
__global__ void convert_kernel(const void* __restrict__ src,
                               uint16_t* __restrict__ dst,
                               const int* __restrict__ flagp) {
  int i = blockIdx.x * 256 + threadIdx.x;
  if (*flagp) {
    ((uint4*)dst)[i] = ((const uint4*)src)[i];
  } else {
    const float* s = (const float*)src + (size_t)i * 8;
    ((uint4*)dst)[i] = pack8f(*(const float4*)s, *(const float4*)(s + 4));
  }
}

// word[b,:] = embed_table[start_ids[b], :]  -> bf16 [512,512]
__global__ void word_kernel(const int* __restrict__ ids,
                            const void* __restrict__ embed,
                            uint16_t* __restrict__ word,
                            const int* __restrict__ flagp) {
  int c = blockIdx.x * 256 + threadIdx.x;  // 32768 chunks of 8 elems
  int b = c >> 6, off = c & 63;
  size_t row = (size_t)ids[b] * 512;
  if (*flagp) {
    ((uint4*)word)[c] = ((const uint4*)((const uint16_t*)embed + row))[off];
  } else {
    const float* s = (const float*)embed + row + (size_t)off * 8;
    ((uint4*)word)[c] = pack8f(*(const float4*)s, *(const float4*)(s + 4));
  }
}

// bias2[j] = b_ih[j] + b_hh[j] + sum_f b_proj[f] * W_ih[j,f]
__global__ void bias2_kernel(const void* __restrict__ bih,
                             const void* __restrict__ bhh,
                             const void* __restrict__ bproj,
                             const uint16_t* __restrict__ Wihb,
                             float* __restrict__ bias2,
                             const int* __restrict__ flagp) {
  int j = blockIdx.x * 256 + threadIdx.x;  // 2048
  int fl = *flagp;
  float s;
  if (fl) s = b2f(((const uint16_t*)bih)[j]) + b2f(((const uint16_t*)bhh)[j]);
  else    s = ((const float*)bih)[j] + ((const float*)bhh)[j];
  const uint16_t* wrow = Wihb + (size_t)j * 1024;
  float acc = 0.f;
  for (int f = 0; f < 512; f++) {
    float bp = fl ? b2f(((const uint16_t*)bproj)[f]) : ((const float*)bproj)[f];
    acc += bp * b2f(wrow[f]);
  }
  bias2[j] = s + acc;
}

// -------------------------------------------------------------------------
// C[M,N] = A[M,K] @ Bt[N,K]^T  (bf16 in, fp32 acc), 128x128 tile, BK=32.
// MODE 0: C bf16 row-major (ldc).
// MODE 1: chunked xgates: local row m -> b=m>>4, t0=m&15; A row = b*80+c0+t0;
//         C row t0*512+b, ldc=2048, += wg[b*2048+col], fp32 store.
// MODE 2: C fp32 (ldc), += wg[col].
// APOLY: A dtype per *flagp (0 -> fp32, converted on the fly).
template <int MODE, bool APOLY>
__global__ __launch_bounds__(256, 2)
void gemm_bt(const void* __restrict__ Av, int lda,
             const uint16_t* __restrict__ Bt, int ldb,
             void* __restrict__ Cout, int ldc, int K,
             const float* __restrict__ wg,
             const int* __restrict__ flagp, int c0) {
  __shared__ __align__(16) uint16_t As[128 * 32];
  __shared__ __align__(16) uint16_t Bs[128 * 32];
  const int tid = threadIdx.x;
  const int bm = blockIdx.y * 128, bn = blockIdx.x * 128;
  const int wid = tid >> 6, lane = tid & 63;
  const int wm = (wid >> 1) * 64, wn = (wid & 1) * 64;
  const int lrow = lane & 15, quad = lane >> 4;
  const int srow = tid >> 2, scol = (tid & 3) * 8;
  const bool a_bf16 = APOLY ? (*flagp != 0) : true;

  int r0 = bm + srow, r1 = bm + 64 + srow;
  size_t gr0, gr1;
  if (MODE == 1) {
    gr0 = (size_t)(r0 >> 4) * 80 + c0 + (r0 & 15);
    gr1 = (size_t)(r1 >> 4) * 80 + c0 + (r1 & 15);
  } else {
    gr0 = r0; gr1 = r1;
  }
  f32x4 acc[4][4] = {};

  for (int kb = 0; kb < K; kb += 32) {
    uint4 a0, a1;
    if (a_bf16) {
      a0 = *(const uint4*)((const uint16_t*)Av + gr0 * lda + kb + scol);
      a1 = *(const uint4*)((const uint16_t*)Av + gr1 * lda + kb + scol);
    } else {
      const float* p0 = (const float*)Av + gr0 * lda + kb + scol;
      const float* p1 = (const float*)Av + gr1 * lda + kb + scol;
      a0 = pack8f(*(const float4*)p0, *(const float4*)(p0 + 4));
      a1 = pack8f(*(const float4*)p1, *(const float4*)(p1 + 4));
    }
    uint4 b0 = *(const uint4*)(Bt + (size_t)(bn + srow) * ldb + kb + scol);
    uint4 b1 = *(const uint4*)(Bt + (size_t)(bn + 64 + srow) * ldb + kb + scol);
    __syncthreads();
    *(uint4*)(As + srow * 32 + scol) = a0;
    *(uint4*)(As + (64 + srow) * 32 + scol) = a1;
    *(uint4*)(Bs + srow * 32 + scol) = b0;
    *(uint4*)(Bs + (64 + srow) * 32 + scol) = b1;
    __syncthreads();
    bf16x8 af[4], bfr[4];
#pragma unroll
    for (int i = 0; i < 4; i++) {
      af[i]  = *reinterpret_cast<const bf16x8*>(As + (wm + i * 16 + lrow) * 32 + quad * 8);
      bfr[i] = *reinterpret_cast<const bf16x8*>(Bs + (wn + i * 16 + lrow) * 32 + quad * 8);
    }
#pragma unroll
    for (int i = 0; i < 4; i++)
#pragma unroll
      for (int j = 0; j < 4; j++)
        acc[i][j] = __builtin_amdgcn_mfma_f32_16x16x32_bf16(af[i], bfr[j], acc[i][j], 0, 0, 0);
  }

  if constexpr (MODE == 0) {
    uint16_t* C = (uint16_t*)Cout;
#pragma unroll
    for (int i = 0; i < 4; i++) {
      int row = bm + wm + i * 16 + quad * 4;
#pragma unroll
      for (int j = 0; j < 4; j++) {
        int col = bn + wn + j * 16 + lrow;
#pragma unroll
        for (int r = 0; r < 4; r++)
          C[(size_t)(row + r) * ldc + col] = f2b(acc[i][j][r]);
      }
    }
  } else if constexpr (MODE == 2) {
    float* C = (float*)Cout;
#pragma unroll
    for (int i = 0; i < 4; i++) {
      int row = bm + wm + i * 16 + quad * 4;
#pragma unroll
      for (int j = 0; j < 4; j++) {
        int col = bn + wn + j * 16 + lrow;
        float bias = wg[col];
#pragma unroll
        for (int r = 0; r < 4; r++)
          C[(size_t)(row + r) * ldc + col] = acc[i][j][r] + bias;
      }
    }
  } else {  // MODE 1
    float* C = (float*)Cout;
#pragma unroll
    for (int i = 0; i < 4; i++) {
#pragma unroll
      for (int r = 0; r < 4; r++) {
        int m = bm + wm + i * 16 + quad * 4 + r;
        int b = m >> 4, t0 = m & 15;
        size_t orow = (size_t)t0 * 512 + b;
#pragma unroll
        for (int j = 0; j < 4; j++) {
          int col = bn + wn + j * 16 + lrow;
          C[orow * 2048 + col] = acc[i][j][r] + wg[(size_t)b * 2048 + col];
        }
      }
    }
  }
}

// -------------------------------------------------------------------------
// Persistent 16-step LSTM kernel (cooperative, 256 WGs x 256 threads).
// WG (rb,cb): batch rows rb*32..+32, h cols cb*32..+32. Wave = gate.
// - Whh B-fragments held in VGPRs across all 16 steps (128 VGPR/lane).
// - c-state in registers (f32x4/thread), persisted to cst at kernel end.
// - h exchanged via double-buffered global + per-rb-group (16 WG) barriers:
//   monotonic device-scope counters, one sync per step. Groups are
//   independent (each needs only its own batch rows), so no grid-wide sync.
// - bid mapping rb=((bid&7)<<1)|((bid>>3)&1): group members share bid%8
//   (same XCD under round-robin dispatch) -> cheaper sync; correctness does
//   not depend on the mapping (device-scope fences either way).
__global__ __launch_bounds__(256, 1)
void lstm16_kernel(const uint16_t* __restrict__ Whhb,   // [2048,512] bf16
                   const float* __restrict__ xg,        // [16,512,2048] f32
                   uint16_t* __restrict__ hb0,
                   uint16_t* __restrict__ hb1,
                   float* __restrict__ cst,             // [512,512] f32
                   void* __restrict__ out,
                   int tbase,
                   const int* __restrict__ flagp,
                   unsigned int* __restrict__ bar) {
  __shared__ __align__(16) uint16_t Hs[32 * 512];  // 32 KB, XOR-swizzled rows
  __shared__ float Gs[4][32][33];                  // 16.9 KB gate staging

  const int tid = threadIdx.x;
  const int bid = blockIdx.x;
  const int rb = ((bid & 7) << 1) | ((bid >> 3) & 1);  // 0..15
  const int cb = bid >> 4;                             // 0..15
  const int g = tid >> 6;                              // wave = gate (i,f,g,o)
  const int lane = tid & 63;
  const int lrow = lane & 15, quad = lane >> 4;
  const int fl = *flagp;

  // ---- Whh B-fragments for this wave's 32 gate-rows, all K (once) ----
  bf16x8 breg[2][16];
  {
    const uint16_t* wb = Whhb + ((size_t)(g * 512 + cb * 32 + lrow) * 512) + quad * 8;
#pragma unroll
    for (int j = 0; j < 2; j++)
#pragma unroll
      for (int kk = 0; kk < 16; kk++)
        breg[j][kk] = *reinterpret_cast<const bf16x8*>(wb + (size_t)j * 16 * 512 + kk * 32);
  }

  // ---- epilogue mapping: thread -> (row, 4 consecutive h cols) ----
  const int erow = tid >> 3;        // 0..31
  const int ecol = (tid & 7) * 4;   // 0..28
  const int gb = rb * 32 + erow;    // global batch row
  const int gh = cb * 32 + ecol;    // global h col
  f32x4 creg = *reinterpret_cast<const f32x4*>(cst + (size_t)gb * 512 + gh);

  const int sc16 = (tid & 7) * 16;  // staging byte-col base
  const int ssw = (erow & 7) << 4;  // staging row swizzle
  unsigned int* cnt = bar + rb * 64;  // 256 B apart per group

#pragma unroll 1
  for (int s = 0; s < 16; s++) {
    const int t = tbase + s;
    const uint16_t* hin = (t & 1) ? hb1 : hb0;
    uint16_t* hout = (t & 1) ? hb0 : hb1;

    // xg prefetch (independent of h; hides L2/L3 latency under the GEMM)
    const float* xr = xg + ((size_t)s * 512 + gb) * 2048 + gh;
    f32x4 x0 = *reinterpret_cast<const f32x4*>(xr);
    f32x4 x1 = *reinterpret_cast<const f32x4*>(xr + 512);
    f32x4 x2 = *reinterpret_cast<const f32x4*>(xr + 1024);
    f32x4 x3 = *reinterpret_cast<const f32x4*>(xr + 1536);

    // stage h(t-1)[rb rows, all 512 cols] into LDS, swizzled
    {
      const char* hsrc = (const char*)(hin + (size_t)gb * 512);
      char* hdst = (char*)Hs + erow * 1024;
#pragma unroll
      for (int it = 0; it < 8; it++) {
        int bc = sc16 + it * 128;
        *reinterpret_cast<uint4*>(hdst + (bc ^ ssw)) =
            *reinterpret_cast<const uint4*>(hsrc + bc);
      }
    }
    __syncthreads();

    // GEMM: gate-g preacts [32 x 32], K=512 from registers(B) x LDS(A)
    f32x4 acc[2][2] = {};
#pragma unroll
    for (int kk = 0; kk < 16; kk++) {
      bf16x8 af[2];
#pragma unroll
      for (int i = 0; i < 2; i++) {
        int r = i * 16 + lrow;
        int bc = kk * 64 + quad * 16;
        af[i] = *reinterpret_cast<const bf16x8*>(
            (const char*)Hs + r * 1024 + (bc ^ ((r & 7) << 4)));
      }
#pragma unroll
      for (int i = 0; i < 2; i++)
#pragma unroll
        for (int j = 0; j < 2; j++)
          acc[i][j] = __builtin_amdgcn_mfma_f32_16x16x32_bf16(af[i], breg[j][kk], acc[i][j], 0, 0, 0);
    }

#pragma unroll
    for (int i = 0; i < 2; i++)
#pragma unroll
      for (int j = 0; j < 2; j++)
#pragma unroll
        for (int r = 0; r < 4; r++)
          Gs[g][i * 16 + quad * 4 + r][j * 16 + lrow] = acc[i][j][r];
    __syncthreads();

    // epilogue: 4 outputs/thread, c in registers
    float hnv[4];
#pragma unroll
    for (int e = 0; e < 4; e++) {
      float p_i = Gs[0][erow][ecol + e] + x0[e];
      float p_f = Gs[1][erow][ecol + e] + x1[e];
      float p_g = Gs[2][erow][ecol + e] + x2[e];
      float p_o = Gs[3][erow][ecol + e] + x3[e];
      float si = 1.f / (1.f + expf(-p_i));
      float sf = 1.f / (1.f + expf(-p_f));
      float so = 1.f / (1.f + expf(-p_o));
      float tg = tanhf(p_g);
      float cn = sf * creg[e] + si * tg;
      creg[e] = cn;
      hnv[e] = so * tanhf(cn);
    }
    uint2 hp;
    hp.x = (uint32_t)f2b(hnv[0]) | ((uint32_t)f2b(hnv[1]) << 16);
    hp.y = (uint32_t)f2b(hnv[2]) | ((uint32_t)f2b(hnv[3]) << 16);
    *reinterpret_cast<uint2*>(hout + (size_t)gb * 512 + gh) = hp;
    size_t oi = (size_t)gb * (80 * 512) + (size_t)t * 512 + gh;
    if (fl) {
      *reinterpret_cast<uint2*>((uint16_t*)out + oi) = hp;
    } else {
      float4 ov = make_float4(hnv[0], hnv[1], hnv[2], hnv[3]);
      *reinterpret_cast<float4*>((float*)out + oi) = ov;
    }

    // group barrier: release own h writes, arrive, wait for 16 arrivals
    __threadfence();
    __syncthreads();
    if (tid == 0) {
      __hip_atomic_fetch_add(cnt, 1u, __ATOMIC_RELEASE, __HIP_MEMORY_SCOPE_AGENT);
      if (s != 15) {  // last step: arrive only; kernel end is the release
        unsigned tgt = (unsigned)(t + 1) * 16u;
        while (__hip_atomic_load(cnt, __ATOMIC_ACQUIRE, __HIP_MEMORY_SCOPE_AGENT) < tgt)
          __builtin_amdgcn_s_sleep(1);
      }
    }
    __syncthreads();
    __threadfence();  // acquire: invalidate stale h lines before next stage
  }

  *reinterpret_cast<f32x4*>(cst + (size_t)gb * 512 + gh) = creg;
}

// -------------------------------------------------------------------------
extern "C" void kernel_launch(void* const* d_in, const int* in_sizes, int n_in,
                              void* d_out, int out_size, void* d_ws, size_t ws_size,
                              hipStream_t stream) {
  const void* enc   = d_in[0];            // [512,80,1024]
  const int*  ids   = (const int*)d_in[1];
  const void* Wproj = d_in[2];            // [1024,512]
  const void* bproj = d_in[3];
  const void* embed = d_in[4];            // [10000,512]
  const void* Wih   = d_in[5];            // [2048,1024]
  const void* Whh   = d_in[6];            // [2048,512]
  const void* bih   = d_in[7];
  const void* bhh   = d_in[8];

  uint8_t* w = (uint8_t*)d_ws;
  int*      flag   = (int*)w;                    // 16 KB reserved
  unsigned int* bar = (unsigned int*)(w + 8192); // 4 KB barrier counters
  float*    bias2  = (float*)(w + 16384);        // 8 KB
  float*    wgates = (float*)(w + 32768);        // [512,2048] f32, 4 MB
  uint16_t* combT  = (uint16_t*)(w + 4227072);   // [2048,1024] bf16, 4 MB
  uint16_t* Wihb   = (uint16_t*)(w + 8421376);   // [2048,1024] bf16, 4 MB
  uint16_t* Whhb   = (uint16_t*)(w + 12615680);  // [2048,512] bf16, 2 MB
  uint16_t* Wprojb = (uint16_t*)(w + 14712832);  // [1024,512] bf16, 1 MB
  uint16_t* word   = (uint16_t*)(w + 15761408);  // [512,512] bf16, 512 KB
  uint16_t* hbuf0  = (uint16_t*)(w + 16285696);  // 512 KB
  uint16_t* hbuf1  = (uint16_t*)(w + 16809984);  // 512 KB
  float*    cst    = (float*)(w + 17334272);     // [512,512] f32, 1 MB
  float*    xgbuf  = (float*)(w + 18382848);     // [16,512,2048] f32, 64 MB

  detect_kernel<<<1, 256, 0, stream>>>((const uint32_t*)Wproj, flag);
  convert_kernel<<<1024, 256, 0, stream>>>(Wih, Wihb, flag);     // 2M elems
  convert_kernel<<<512, 256, 0, stream>>>(Whh, Whhb, flag);      // 1M
  convert_kernel<<<256, 256, 0, stream>>>(Wproj, Wprojb, flag);  // 512K
  word_kernel<<<128, 256, 0, stream>>>(ids, embed, word, flag);
  bias2_kernel<<<8, 256, 0, stream>>>(bih, bhh, bproj, Wihb, bias2, flag);

  // combT[j,d] = sum_f W_ih[j,f] * W_proj[d,f]   (M=2048,N=1024,K=512)
  gemm_bt<0, false><<<dim3(8, 16), 256, 0, stream>>>(Wihb, 1024, Wprojb, 512,
                                                     combT, 1024, 512, nullptr, flag, 0);
  // wgates[b,j] = sum_w word[b,w]*W_ih[j,512+w] + bias2[j]  (M=512,N=2048,K=512)
  gemm_bt<2, false><<<dim3(16, 4), 256, 0, stream>>>(word, 512, Wihb + 512, 1024,
                                                     wgates, 2048, 512, bias2, flag, 0);

  (void)hipMemsetAsync(hbuf0, 0, 512 * 512 * 2, stream);
  (void)hipMemsetAsync(cst, 0, 512 * 512 * 4, stream);
  (void)hipMemsetAsync(bar, 0, 4096, stream);

  const uint16_t* Whhb_a = Whhb;
  const float* xg_a = xgbuf;
  uint16_t* hb0_a = hbuf0;
  uint16_t* hb1_a = hbuf1;
  float* cst_a = cst;
  void* out_a = d_out;
  const int* flag_a = flag;
  unsigned int* bar_a = bar;

  for (int c = 0; c < 5; c++) {
    // xgbuf[t0,b,j] = sum_d enc[b,c*16+t0,d]*combT[j,d] + wgates[b,j]
    gemm_bt<1, true><<<dim3(16, 64), 256, 0, stream>>>(enc, 1024, combT, 1024,
                                                       xgbuf, 2048, 1024, wgates, flag, c * 16);
    int tbase = c * 16;
    void* kargs[] = {(void*)&Whhb_a, (void*)&xg_a, (void*)&hb0_a, (void*)&hb1_a,
                     (void*)&cst_a, (void*)&out_a, (void*)&tbase, (void*)&flag_a,
                     (void*)&bar_a};
    (void)hipLaunchCooperativeKernel(lstm16_kernel, dim3(256), dim3(256), kargs,
                                     0u, stream);
  }
}

// Round 3
// 1097.377 us; speedup vs baseline: 4.0886x; 4.0886x over previous
//
#include <hip/hip_runtime.h>
#include <stdint.h>

typedef __bf16 bf16x8 __attribute__((ext_vector_type(8)));
typedef float  f32x4  __attribute__((ext_vector_type(4)));
typedef unsigned int u32x4 __attribute__((ext_vector_type(4)));
typedef unsigned long long u64;

__device__ __forceinline__ uint16_t f2b(float f) {
  uint32_t u = __float_as_uint(f);
  return (uint16_t)((u + 0x7FFFu + ((u >> 16) & 1u)) >> 16);
}
__device__ __forceinline__ float b2f(uint16_t h) {
  return __uint_as_float(((uint32_t)h) << 16);
}
__device__ __forceinline__ uint4 pack8f(float4 a, float4 b) {
  uint4 r;
  r.x = (uint32_t)f2b(a.x) | ((uint32_t)f2b(a.y) << 16);
  r.y = (uint32_t)f2b(a.z) | ((uint32_t)f2b(a.w) << 16);
  r.z = (uint32_t)f2b(b.x) | ((uint32_t)f2b(b.y) << 16);
  r.w = (uint32_t)f2b(b.z) | ((uint32_t)f2b(b.w) << 16);
  return r;
}
__device__ __forceinline__ float fsig(float x) {
  return 1.f / (1.f + __expf(-x));
}
__device__ __forceinline__ float ftanh(float x) {
  return 1.f - 2.f / (1.f + __expf(2.f * x));
}

// -------------------------------------------------------------------------
// Dtype detector: if W_proj is bf16-packed, low 16 bits of each u32 word are a
// plausible N(0,0.02) bf16 sample (~99.6% in (1e-4,0.5)); if fp32, low bits are
// mantissa noise (~5% pass). flag=1 -> bf16 buffers, flag=0 -> fp32 buffers.
__global__ void detect_kernel(const uint32_t* __restrict__ wproj, int* flag) {
  __shared__ int cnt;
  if (threadIdx.x == 0) cnt = 0;
  __syncthreads();
  int local = 0;
  for (int i = threadIdx.x; i < 1024; i += 256) {
    float v = __uint_as_float((wproj[i] & 0xFFFFu) << 16);
    float av = fabsf(v);
    if (av > 1e-4f && av < 0.5f) local++;
  }
  atomicAdd(&cnt, local);
  __syncthreads();
  if (threadIdx.x == 0) flag[0] = (cnt > 512) ? 1 : 0;
}

// Convert n elements (n % 2048 == 0) to canonical bf16. One thread = 8 elems.
__global__ void convert_kernel(const void* __restrict__ src,
                               uint16_t* __restrict__ dst,
                               const int* __restrict__ flagp) {
  int i = blockIdx.x * 256 + threadIdx.x;
  if (*flagp) {
    ((uint4*)dst)[i] = ((const uint4*)src)[i];
  } else {
    const float* s = (const float*)src + (size_t)i * 8;
    ((uint4*)dst)[i] = pack8f(*(const float4*)s, *(const float4*)(s + 4));
  }
}

// word[b,:] = embed_table[start_ids[b], :]  -> bf16 [512,512]
__global__ void word_kernel(const int* __restrict__ ids,
                            const void* __restrict__ embed,
                            uint16_t* __restrict__ word,
                            const int* __restrict__ flagp) {
  int c = blockIdx.x * 256 + threadIdx.x;  // 32768 chunks of 8 elems
  int b = c >> 6, off = c & 63;
  size_t row = (size_t)ids[b] * 512;
  if (*flagp) {
    ((uint4*)word)[c] = ((const uint4*)((const uint16_t*)embed + row))[off];
  } else {
    const float* s = (const float*)embed + row + (size_t)off * 8;
    ((uint4*)word)[c] = pack8f(*(const float4*)s, *(const float4*)(s + 4));
  }
}

// bias2[j] = b_ih[j] + b_hh[j] + sum_f b_proj[f] * W_ih[j,f]
__global__ void bias2_kernel(const void* __restrict__ bih,
                             const void* __restrict__ bhh,
                             const void* __restrict__ bproj,
                             const uint16_t* __restrict__ Wihb,
                             float* __restrict__ bias2,
                             const int* __restrict__ flagp) {
  int j = blockIdx.x * 256 + threadIdx.x;  // 2048
  int fl = *flagp;
  float s;
  if (fl) s = b2f(((const uint16_t*)bih)[j]) + b2f(((const uint16_t*)bhh)[j]);
  else    s = ((const float*)bih)[j] + ((const float*)bhh)[j];
  const uint16_t* wrow = Wihb + (size_t)j * 1024;
  float acc = 0.f;
  for (int f = 0; f < 512; f++) {
    float bp = fl ? b2f(((const uint16_t*)bproj)[f]) : ((const float*)bproj)[f];
    acc += bp * b2f(wrow[f]);
  }
  bias2[j] = s + acc;
}

// -------------------------------------------------------------------------
// C[M,N] = A[M,K] @ Bt[N,K]^T  (bf16 in, fp32 acc), 128x128 tile, BK=32.
// MODE 0: C bf16 row-major (ldc).
// MODE 1: chunked xgates: local row m -> b=m>>4, t0=m&15; A row = b*80+c0+t0;
//         C row t0*512+b, ldc=2048, += wg[b*2048+col], fp32 store.
// MODE 2: C fp32 (ldc), += wg[col].
// APOLY: A dtype per *flagp (0 -> fp32, converted on the fly).
template <int MODE, bool APOLY>
__global__ __launch_bounds__(256, 2)
void gemm_bt(const void* __restrict__ Av, int lda,
             const uint16_t* __restrict__ Bt, int ldb,
             void* __restrict__ Cout, int ldc, int K,
             const float* __restrict__ wg,
             const int* __restrict__ flagp, int c0) {
  __shared__ __align__(16) uint16_t As[128 * 32];
  __shared__ __align__(16) uint16_t Bs[128 * 32];
  const int tid = threadIdx.x;
  const int bm = blockIdx.y * 128, bn = blockIdx.x * 128;
  const int wid = tid >> 6, lane = tid & 63;
  const int wm = (wid >> 1) * 64, wn = (wid & 1) * 64;
  const int lrow = lane & 15, quad = lane >> 4;
  const int srow = tid >> 2, scol = (tid & 3) * 8;
  const bool a_bf16 = APOLY ? (*flagp != 0) : true;

  int r0 = bm + srow, r1 = bm + 64 + srow;
  size_t gr0, gr1;
  if (MODE == 1) {
    gr0 = (size_t)(r0 >> 4) * 80 + c0 + (r0 & 15);
    gr1 = (size_t)(r1 >> 4) * 80 + c0 + (r1 & 15);
  } else {
    gr0 = r0; gr1 = r1;
  }
  f32x4 acc[4][4] = {};

  for (int kb = 0; kb < K; kb += 32) {
    uint4 a0, a1;
    if (a_bf16) {
      a0 = *(const uint4*)((const uint16_t*)Av + gr0 * lda + kb + scol);
      a1 = *(const uint4*)((const uint16_t*)Av + gr1 * lda + kb + scol);
    } else {
      const float* p0 = (const float*)Av + gr0 * lda + kb + scol;
      const float* p1 = (const float*)Av + gr1 * lda + kb + scol;
      a0 = pack8f(*(const float4*)p0, *(const float4*)(p0 + 4));
      a1 = pack8f(*(const float4*)p1, *(const float4*)(p1 + 4));
    }
    uint4 b0 = *(const uint4*)(Bt + (size_t)(bn + srow) * ldb + kb + scol);
    uint4 b1 = *(const uint4*)(Bt + (size_t)(bn + 64 + srow) * ldb + kb + scol);
    __syncthreads();
    *(uint4*)(As + srow * 32 + scol) = a0;
    *(uint4*)(As + (64 + srow) * 32 + scol) = a1;
    *(uint4*)(Bs + srow * 32 + scol) = b0;
    *(uint4*)(Bs + (64 + srow) * 32 + scol) = b1;
    __syncthreads();
    bf16x8 af[4], bfr[4];
#pragma unroll
    for (int i = 0; i < 4; i++) {
      af[i]  = *reinterpret_cast<const bf16x8*>(As + (wm + i * 16 + lrow) * 32 + quad * 8);
      bfr[i] = *reinterpret_cast<const bf16x8*>(Bs + (wn + i * 16 + lrow) * 32 + quad * 8);
    }
#pragma unroll
    for (int i = 0; i < 4; i++)
#pragma unroll
      for (int j = 0; j < 4; j++)
        acc[i][j] = __builtin_amdgcn_mfma_f32_16x16x32_bf16(af[i], bfr[j], acc[i][j], 0, 0, 0);
  }

  if constexpr (MODE == 0) {
    uint16_t* C = (uint16_t*)Cout;
#pragma unroll
    for (int i = 0; i < 4; i++) {
      int row = bm + wm + i * 16 + quad * 4;
#pragma unroll
      for (int j = 0; j < 4; j++) {
        int col = bn + wn + j * 16 + lrow;
#pragma unroll
        for (int r = 0; r < 4; r++)
          C[(size_t)(row + r) * ldc + col] = f2b(acc[i][j][r]);
      }
    }
  } else if constexpr (MODE == 2) {
    float* C = (float*)Cout;
#pragma unroll
    for (int i = 0; i < 4; i++) {
      int row = bm + wm + i * 16 + quad * 4;
#pragma unroll
      for (int j = 0; j < 4; j++) {
        int col = bn + wn + j * 16 + lrow;
        float bias = wg[col];
#pragma unroll
        for (int r = 0; r < 4; r++)
          C[(size_t)(row + r) * ldc + col] = acc[i][j][r] + bias;
      }
    }
  } else {  // MODE 1
    float* C = (float*)Cout;
#pragma unroll
    for (int i = 0; i < 4; i++) {
#pragma unroll
      for (int r = 0; r < 4; r++) {
        int m = bm + wm + i * 16 + quad * 4 + r;
        int b = m >> 4, t0 = m & 15;
        size_t orow = (size_t)t0 * 512 + b;
#pragma unroll
        for (int j = 0; j < 4; j++) {
          int col = bn + wn + j * 16 + lrow;
          C[orow * 2048 + col] = acc[i][j][r] + wg[(size_t)b * 2048 + col];
        }
      }
    }
  }
}

// -------------------------------------------------------------------------
// Persistent 16-step LSTM kernel (cooperative, 256 WGs x 256 threads).
// WG (rb,cb): batch rows rb*32..+32, h cols cb*32..+32. Wave = gate.
// Coherence design (NO agent fences -- they are cache-wide wbl2/inv on
// gfx950 and were the round-1 disaster):
//  - h writes: relaxed agent-scope 8B atomic stores (global_store_dwordx2
//    sc1, write-through past the non-coherent XCD L2 to the LLC).
//  - h reads: PLAIN cached loads from a 17-slot ring. 16 steps/dispatch ->
//    every slot read was written exactly once this dispatch at a fresh
//    address; no cache can hold a stale copy (previous dispatch's lines are
//    invalidated at the kernel-launch boundary).
//  - barrier: __syncthreads() (drains each wave's vmcnt -> sc1 stores are
//    at the LLC) + relaxed agent atomic add + relaxed poll. No fences.
//  - bid mapping rb=((bid&7)<<1)|((bid>>3)&1): all 16 WGs of a batch-group
//    share bid%8 (same XCD under round-robin) -> fresh h lines are pulled
//    from LLC once per XCD and served 16x from L2. Correctness does not
//    depend on the mapping.
// Whh B-fragments are pinned in VGPRs (empty asm) across all 16 steps;
// c-state lives in registers for the whole dispatch.
__global__ __launch_bounds__(256, 1)
void lstm16_kernel(const uint16_t* __restrict__ Whhb,   // [2048,512] bf16
                   const float* __restrict__ xg,        // [16,512,2048] f32
                   uint16_t* __restrict__ hring,        // [17,512,512] bf16
                   float* __restrict__ cst,             // [512,512] f32
                   void* __restrict__ out,
                   int tbase,
                   const int* __restrict__ flagp,
                   unsigned int* __restrict__ bar) {
  __shared__ __align__(16) uint16_t Hs[32 * 512];  // 32 KB, XOR-swizzled rows
  __shared__ float Gs[4][32][33];                  // 16.9 KB gate staging

  const int tid = threadIdx.x;
  const int bid = blockIdx.x;
  const int rb = ((bid & 7) << 1) | ((bid >> 3) & 1);  // 0..15
  const int cb = bid >> 4;                             // 0..15
  const int g = tid >> 6;                              // wave = gate (i,f,g,o)
  const int lane = tid & 63;
  const int lrow = lane & 15, quad = lane >> 4;
  const int fl = *flagp;

  // ---- Whh B-fragments for this wave's 32 gate-rows, all K, pinned ----
  u32x4 breg[2][16];
  {
    const uint16_t* wb = Whhb + ((size_t)(g * 512 + cb * 32 + lrow) * 512) + quad * 8;
#pragma unroll
    for (int j = 0; j < 2; j++)
#pragma unroll
      for (int kk = 0; kk < 16; kk++) {
        breg[j][kk] = *reinterpret_cast<const u32x4*>(wb + (size_t)j * 16 * 512 + kk * 32);
        asm volatile("" : "+v"(breg[j][kk]));  // force resident; block remat
      }
  }

  // ---- epilogue mapping: thread -> (row, 4 consecutive h cols) ----
  const int erow = tid >> 3;        // 0..31
  const int ecol = (tid & 7) * 4;   // 0..28
  const int gb = rb * 32 + erow;    // global batch row
  const int gh = cb * 32 + ecol;    // global h col
  f32x4 creg = *reinterpret_cast<const f32x4*>(cst + (size_t)gb * 512 + gh);

  const int sc16 = (tid & 7) * 16;  // staging byte-col base
  const int ssw = (erow & 7) << 4;  // staging row swizzle
  unsigned int* cnt = bar + rb * 64;  // 256 B apart per group

#pragma unroll 1
  for (int s = 0; s < 16; s++) {
    const int t = tbase + s;
    const uint16_t* hin = hring + (size_t)((t + 16) % 17) * 262144;  // h(t-1)
    uint16_t* hout = hring + (size_t)(t % 17) * 262144;              // h(t)

    // xg prefetch (independent of h; latency hidden under stage+GEMM)
    const float* xr = xg + ((size_t)s * 512 + gb) * 2048 + gh;
    f32x4 x0 = *reinterpret_cast<const f32x4*>(xr);
    f32x4 x1 = *reinterpret_cast<const f32x4*>(xr + 512);
    f32x4 x2 = *reinterpret_cast<const f32x4*>(xr + 1024);
    f32x4 x3 = *reinterpret_cast<const f32x4*>(xr + 1536);

    // stage h(t-1)[rb rows, all 512 cols] into LDS, swizzled (plain loads)
    {
      const char* hsrc = (const char*)(hin + (size_t)gb * 512);
      char* hdst = (char*)Hs + erow * 1024;
#pragma unroll
      for (int it = 0; it < 8; it++) {
        int bc = sc16 + it * 128;
        *reinterpret_cast<uint4*>(hdst + (bc ^ ssw)) =
            *reinterpret_cast<const uint4*>(hsrc + bc);
      }
    }
    __syncthreads();

    // GEMM: gate-g preacts [32 x 32], K=512 from registers(B) x LDS(A)
    f32x4 acc[2][2] = {};
#pragma unroll
    for (int kk = 0; kk < 16; kk++) {
      bf16x8 af[2];
#pragma unroll
      for (int i = 0; i < 2; i++) {
        int r = i * 16 + lrow;
        int bc = kk * 64 + quad * 16;
        af[i] = *reinterpret_cast<const bf16x8*>(
            (const char*)Hs + r * 1024 + (bc ^ ((r & 7) << 4)));
      }
#pragma unroll
      for (int i = 0; i < 2; i++)
#pragma unroll
        for (int j = 0; j < 2; j++)
          acc[i][j] = __builtin_amdgcn_mfma_f32_16x16x32_bf16(
              af[i], __builtin_bit_cast(bf16x8, breg[j][kk]), acc[i][j], 0, 0, 0);
    }

#pragma unroll
    for (int i = 0; i < 2; i++)
#pragma unroll
      for (int j = 0; j < 2; j++)
#pragma unroll
        for (int r = 0; r < 4; r++)
          Gs[g][i * 16 + quad * 4 + r][j * 16 + lrow] = acc[i][j][r];
    __syncthreads();

    // epilogue: 4 outputs/thread, c in registers
    float hnv[4];
#pragma unroll
    for (int e = 0; e < 4; e++) {
      float p_i = Gs[0][erow][ecol + e] + x0[e];
      float p_f = Gs[1][erow][ecol + e] + x1[e];
      float p_g = Gs[2][erow][ecol + e] + x2[e];
      float p_o = Gs[3][erow][ecol + e] + x3[e];
      float si = fsig(p_i);
      float sf = fsig(p_f);
      float so = fsig(p_o);
      float tg = ftanh(p_g);
      float cn = sf * creg[e] + si * tg;
      creg[e] = cn;
      hnv[e] = so * ftanh(cn);
    }
    uint2 hp;
    hp.x = (uint32_t)f2b(hnv[0]) | ((uint32_t)f2b(hnv[1]) << 16);
    hp.y = (uint32_t)f2b(hnv[2]) | ((uint32_t)f2b(hnv[3]) << 16);
    // h store: write-through to LLC (agent-scope relaxed = sc1), no fence
    u64 hv = (u64)hp.x | ((u64)hp.y << 32);
    __hip_atomic_store((u64*)(hout + (size_t)gb * 512 + gh), hv,
                       __ATOMIC_RELAXED, __HIP_MEMORY_SCOPE_AGENT);
    size_t oi = (size_t)gb * (80 * 512) + (size_t)t * 512 + gh;
    if (fl) {
      *reinterpret_cast<uint2*>((uint16_t*)out + oi) = hp;
    } else {
      float4 ov = make_float4(hnv[0], hnv[1], hnv[2], hnv[3]);
      *reinterpret_cast<float4*>((float*)out + oi) = ov;
    }

    // group barrier: syncthreads drains vmcnt (sc1 stores at LLC), then
    // one relaxed agent atomic arrive + poll. No cache-maintenance ops.
    __syncthreads();
    if (tid == 0) {
      __hip_atomic_fetch_add(cnt, 1u, __ATOMIC_RELAXED, __HIP_MEMORY_SCOPE_AGENT);
      if (s != 15) {  // last step: arrive only (next chunk is stream-ordered)
        unsigned tgt = (unsigned)(t + 1) * 16u;
        while (__hip_atomic_load(cnt, __ATOMIC_RELAXED, __HIP_MEMORY_SCOPE_AGENT) < tgt)
          __builtin_amdgcn_s_sleep(1);
      }
    }
    __syncthreads();
  }

  *reinterpret_cast<f32x4*>(cst + (size_t)gb * 512 + gh) = creg;
}

// -------------------------------------------------------------------------
extern "C" void kernel_launch(void* const* d_in, const int* in_sizes, int n_in,
                              void* d_out, int out_size, void* d_ws, size_t ws_size,
                              hipStream_t stream) {
  const void* enc   = d_in[0];            // [512,80,1024]
  const int*  ids   = (const int*)d_in[1];
  const void* Wproj = d_in[2];            // [1024,512]
  const void* bproj = d_in[3];
  const void* embed = d_in[4];            // [10000,512]
  const void* Wih   = d_in[5];            // [2048,1024]
  const void* Whh   = d_in[6];            // [2048,512]
  const void* bih   = d_in[7];
  const void* bhh   = d_in[8];

  uint8_t* w = (uint8_t*)d_ws;
  int*      flag   = (int*)w;                    // 16 KB reserved
  unsigned int* bar = (unsigned int*)(w + 8192); // 4 KB barrier counters
  float*    bias2  = (float*)(w + 16384);        // 8 KB
  float*    wgates = (float*)(w + 32768);        // [512,2048] f32, 4 MB
  uint16_t* combT  = (uint16_t*)(w + 4227072);   // [2048,1024] bf16, 4 MB
  uint16_t* Wihb   = (uint16_t*)(w + 8421376);   // [2048,1024] bf16, 4 MB
  uint16_t* Whhb   = (uint16_t*)(w + 12615680);  // [2048,512] bf16, 2 MB
  uint16_t* Wprojb = (uint16_t*)(w + 14712832);  // [1024,512] bf16, 1 MB
  uint16_t* word   = (uint16_t*)(w + 15761408);  // [512,512] bf16, 512 KB
  float*    cst    = (float*)(w + 17334272);     // [512,512] f32, 1 MB
  float*    xgbuf  = (float*)(w + 18382848);     // [16,512,2048] f32, 64 MB
  uint16_t* hring  = (uint16_t*)(w + 85491712);  // [17,512,512] bf16, 8.9 MB

  detect_kernel<<<1, 256, 0, stream>>>((const uint32_t*)Wproj, flag);
  convert_kernel<<<1024, 256, 0, stream>>>(Wih, Wihb, flag);     // 2M elems
  convert_kernel<<<512, 256, 0, stream>>>(Whh, Whhb, flag);      // 1M
  convert_kernel<<<256, 256, 0, stream>>>(Wproj, Wprojb, flag);  // 512K
  word_kernel<<<128, 256, 0, stream>>>(ids, embed, word, flag);
  bias2_kernel<<<8, 256, 0, stream>>>(bih, bhh, bproj, Wihb, bias2, flag);

  // combT[j,d] = sum_f W_ih[j,f] * W_proj[d,f]   (M=2048,N=1024,K=512)
  gemm_bt<0, false><<<dim3(8, 16), 256, 0, stream>>>(Wihb, 1024, Wprojb, 512,
                                                     combT, 1024, 512, nullptr, flag, 0);
  // wgates[b,j] = sum_w word[b,w]*W_ih[j,512+w] + bias2[j]  (M=512,N=2048,K=512)
  gemm_bt<2, false><<<dim3(16, 4), 256, 0, stream>>>(word, 512, Wihb + 512, 1024,
                                                     wgates, 2048, 512, bias2, flag, 0);

  (void)hipMemsetAsync(hring + (size_t)16 * 262144, 0, 524288, stream);  // h(-1)=0
  (void)hipMemsetAsync(cst, 0, 512 * 512 * 4, stream);
  (void)hipMemsetAsync(bar, 0, 4096, stream);

  const uint16_t* Whhb_a = Whhb;
  const float* xg_a = xgbuf;
  uint16_t* hring_a = hring;
  float* cst_a = cst;
  void* out_a = d_out;
  const int* flag_a = flag;
  unsigned int* bar_a = bar;

  for (int c = 0; c < 5; c++) {
    // xgbuf[t0,b,j] = sum_d enc[b,c*16+t0,d]*combT[j,d] + wgates[b,j]
    gemm_bt<1, true><<<dim3(16, 64), 256, 0, stream>>>(enc, 1024, combT, 1024,
                                                       xgbuf, 2048, 1024, wgates, flag, c * 16);
    int tbase = c * 16;
    void* kargs[] = {(void*)&Whhb_a, (void*)&xg_a, (void*)&hring_a,
                     (void*)&cst_a, (void*)&out_a, (void*)&tbase, (void*)&flag_a,
                     (void*)&bar_a};
    (void)hipLaunchCooperativeKernel(lstm16_kernel, dim3(256), dim3(256), kargs,
                                     0u, stream);
  }
}

// Round 7
// 958.596 us; speedup vs baseline: 4.6805x; 1.1448x over previous
//
#include <hip/hip_runtime.h>
#include <stdint.h>

typedef __bf16 bf16x8 __attribute__((ext_vector_type(8)));
typedef float  f32x4  __attribute__((ext_vector_type(4)));
typedef unsigned int u32x4 __attribute__((ext_vector_type(4)));
typedef unsigned long long u64;

__device__ __forceinline__ uint16_t f2b(float f) {
  uint32_t u = __float_as_uint(f);
  return (uint16_t)((u + 0x7FFFu + ((u >> 16) & 1u)) >> 16);
}
__device__ __forceinline__ float b2f(uint16_t h) {
  return __uint_as_float(((uint32_t)h) << 16);
}
__device__ __forceinline__ uint4 pack8f(float4 a, float4 b) {
  uint4 r;
  r.x = (uint32_t)f2b(a.x) | ((uint32_t)f2b(a.y) << 16);
  r.y = (uint32_t)f2b(a.z) | ((uint32_t)f2b(a.w) << 16);
  r.z = (uint32_t)f2b(b.x) | ((uint32_t)f2b(b.y) << 16);
  r.w = (uint32_t)f2b(b.z) | ((uint32_t)f2b(b.w) << 16);
  return r;
}
__device__ __forceinline__ float fsig(float x) {
  return 1.f / (1.f + __expf(-x));
}
__device__ __forceinline__ float ftanh(float x) {
  return 1.f - 2.f / (1.f + __expf(2.f * x));
}
// async global->LDS, 16B per lane. LDS dest must be wave-uniform base + lane*16.
__device__ __forceinline__ void gload_lds16(const void* g, void* l) {
  __builtin_amdgcn_global_load_lds(
      (const __attribute__((address_space(1))) uint32_t*)g,
      (__attribute__((address_space(3))) uint32_t*)l, 16, 0, 0);
}

// -------------------------------------------------------------------------
// Dtype detector: if W_proj is bf16-packed, low 16 bits of each u32 word are a
// plausible N(0,0.02) bf16 sample (~99.6% in (1e-4,0.5)); if fp32, low bits are
// mantissa noise (~5% pass). flag=1 -> bf16 buffers, flag=0 -> fp32 buffers.
__global__ void detect_kernel(const uint32_t* __restrict__ wproj, int* flag) {
  __shared__ int cnt;
  if (threadIdx.x == 0) cnt = 0;
  __syncthreads();
  int local = 0;
  for (int i = threadIdx.x; i < 1024; i += 256) {
    float v = __uint_as_float((wproj[i] & 0xFFFFu) << 16);
    float av = fabsf(v);
    if (av > 1e-4f && av < 0.5f) local++;
  }
  atomicAdd(&cnt, local);
  __syncthreads();
  if (threadIdx.x == 0) flag[0] = (cnt > 512) ? 1 : 0;
}

// Convert n elements (n % 2048 == 0) to canonical bf16. One thread = 8 elems.
__global__ void convert_kernel(const void* __restrict__ src,
                               uint16_t* __restrict__ dst,
                               const int* __restrict__ flagp) {
  int i = blockIdx.x * 256 + threadIdx.x;
  if (*flagp) {
    ((uint4*)dst)[i] = ((const uint4*)src)[i];
  } else {
    const float* s = (const float*)src + (size_t)i * 8;
    ((uint4*)dst)[i] = pack8f(*(const float4*)s, *(const float4*)(s + 4));
  }
}

// enc chunk c -> encb[8192,1024] bf16, row m = b*16 + t0 (t0 = t - c0).
// Same f2b rounding as the old in-loop pack8f -> bit-identical GEMM inputs.
__global__ void convA_kernel(const void* __restrict__ enc,
                             uint16_t* __restrict__ encb,
                             const int* __restrict__ flagp, int c0) {
  int i = blockIdx.x * 256 + threadIdx.x;  // 1,048,576 threads, 8 elems each
  int m = i >> 7, ch = i & 127;
  int b = m >> 4, t0 = m & 15;
  size_t src = ((size_t)b * 80 + c0 + t0) * 1024 + (size_t)ch * 8;
  if (*flagp) {
    ((uint4*)encb)[i] = *(const uint4*)((const uint16_t*)enc + src);
  } else {
    const float* s = (const float*)enc + src;
    ((uint4*)encb)[i] = pack8f(*(const float4*)s, *(const float4*)(s + 4));
  }
}

// word[b,:] = embed_table[start_ids[b], :]  -> bf16 [512,512]
__global__ void word_kernel(const int* __restrict__ ids,
                            const void* __restrict__ embed,
                            uint16_t* __restrict__ word,
                            const int* __restrict__ flagp) {
  int c = blockIdx.x * 256 + threadIdx.x;  // 32768 chunks of 8 elems
  int b = c >> 6, off = c & 63;
  size_t row = (size_t)ids[b] * 512;
  if (*flagp) {
    ((uint4*)word)[c] = ((const uint4*)((const uint16_t*)embed + row))[off];
  } else {
    const float* s = (const float*)embed + row + (size_t)off * 8;
    ((uint4*)word)[c] = pack8f(*(const float4*)s, *(const float4*)(s + 4));
  }
}

// bias2[j] = b_ih[j] + b_hh[j] + sum_f b_proj[f] * W_ih[j,f]
// One j per wave (4 waves/WG, 512 WGs), shuffle-reduce across 64 lanes.
__global__ void bias2_kernel(const void* __restrict__ bih,
                             const void* __restrict__ bhh,
                             const void* __restrict__ bproj,
                             const uint16_t* __restrict__ Wihb,
                             float* __restrict__ bias2,
                             const int* __restrict__ flagp) {
  const int wid = threadIdx.x >> 6, lane = threadIdx.x & 63;
  const int j = blockIdx.x * 4 + wid;  // 0..2047
  const int fl = *flagp;
  uint4 wv = *(const uint4*)(Wihb + (size_t)j * 1024 + lane * 8);
  const uint16_t wh[8] = {
      (uint16_t)wv.x, (uint16_t)(wv.x >> 16), (uint16_t)wv.y, (uint16_t)(wv.y >> 16),
      (uint16_t)wv.z, (uint16_t)(wv.z >> 16), (uint16_t)wv.w, (uint16_t)(wv.w >> 16)};
  float bp[8];
  if (fl) {
    uint4 pv = *(const uint4*)((const uint16_t*)bproj + lane * 8);
    const uint16_t ph[8] = {
        (uint16_t)pv.x, (uint16_t)(pv.x >> 16), (uint16_t)pv.y, (uint16_t)(pv.y >> 16),
        (uint16_t)pv.z, (uint16_t)(pv.z >> 16), (uint16_t)pv.w, (uint16_t)(pv.w >> 16)};
#pragma unroll
    for (int e = 0; e < 8; e++) bp[e] = b2f(ph[e]);
  } else {
    float4 p0 = ((const float4*)bproj)[lane * 2];
    float4 p1 = ((const float4*)bproj)[lane * 2 + 1];
    bp[0] = p0.x; bp[1] = p0.y; bp[2] = p0.z; bp[3] = p0.w;
    bp[4] = p1.x; bp[5] = p1.y; bp[6] = p1.z; bp[7] = p1.w;
  }
  float acc = 0.f;
#pragma unroll
  for (int e = 0; e < 8; e++) acc += bp[e] * b2f(wh[e]);
#pragma unroll
  for (int m = 32; m >= 1; m >>= 1) acc += __shfl_xor(acc, m, 64);
  if (lane == 0) {
    float s;
    if (fl) s = b2f(((const uint16_t*)bih)[j]) + b2f(((const uint16_t*)bhh)[j]);
    else    s = ((const float*)bih)[j] + ((const float*)bhh)[j];
    bias2[j] = s + acc;
  }
}

// -------------------------------------------------------------------------
// C[M,N] = A[M,K] @ Bt[N,K]^T  (bf16 in, fp32 acc), 128x128 tile, BK=32.
// Staging via global_load_lds width=16 (async, no VGPR round-trip). LDS
// layout is exactly base + lane*16 per wave, as the instruction requires.
// MODE 0: C bf16 row-major (ldc).
// MODE 1: chunked xgates: A = encb (row m = b*16+t0, linear); C row t0*512+b,
//         ldc=2048, += wg[b*2048+col], fp32 store.
// MODE 2: C fp32 (ldc), += wg[col].
template <int MODE>
__global__ __launch_bounds__(256, 2)
void gemm_bt(const uint16_t* __restrict__ A, int lda,
             const uint16_t* __restrict__ Bt, int ldb,
             void* __restrict__ Cout, int ldc, int K,
             const float* __restrict__ wg) {
  __shared__ __align__(16) uint16_t As[128 * 32];
  __shared__ __align__(16) uint16_t Bs[128 * 32];
  const int tid = threadIdx.x;
  const int bm = blockIdx.y * 128, bn = blockIdx.x * 128;
  const int wid = tid >> 6, lane = tid & 63;
  const int wm = (wid >> 1) * 64, wn = (wid & 1) * 64;
  const int lrow = lane & 15, quad = lane >> 4;
  const int srow = tid >> 2, scol = (tid & 3) * 8;

  const uint16_t* ga0 = A + (size_t)(bm + srow) * lda + scol;
  const uint16_t* ga1 = A + (size_t)(bm + 64 + srow) * lda + scol;
  const uint16_t* gb0 = Bt + (size_t)(bn + srow) * ldb + scol;
  const uint16_t* gb1 = Bt + (size_t)(bn + 64 + srow) * ldb + scol;
  uint16_t* la0 = As + srow * 32 + scol;         // byte off = tid*16
  uint16_t* la1 = As + (64 + srow) * 32 + scol;  // byte off = 4096 + tid*16
  uint16_t* lb0 = Bs + srow * 32 + scol;
  uint16_t* lb1 = Bs + (64 + srow) * 32 + scol;

  f32x4 acc[4][4] = {};

  for (int kb = 0; kb < K; kb += 32) {
    __syncthreads();  // previous iteration's ds_reads complete
    gload_lds16(ga0 + kb, la0);
    gload_lds16(ga1 + kb, la1);
    gload_lds16(gb0 + kb, lb0);
    gload_lds16(gb1 + kb, lb1);
    __syncthreads();  // drains vmcnt -> LDS tiles ready
    bf16x8 af[4], bfr[4];
#pragma unroll
    for (int i = 0; i < 4; i++) {
      af[i]  = *reinterpret_cast<const bf16x8*>(As + (wm + i * 16 + lrow) * 32 + quad * 8);
      bfr[i] = *reinterpret_cast<const bf16x8*>(Bs + (wn + i * 16 + lrow) * 32 + quad * 8);
    }
#pragma unroll
    for (int i = 0; i < 4; i++)
#pragma unroll
      for (int j = 0; j < 4; j++)
        acc[i][j] = __builtin_amdgcn_mfma_f32_16x16x32_bf16(af[i], bfr[j], acc[i][j], 0, 0, 0);
  }

  if constexpr (MODE == 0) {
    uint16_t* C = (uint16_t*)Cout;
#pragma unroll
    for (int i = 0; i < 4; i++) {
      int row = bm + wm + i * 16 + quad * 4;
#pragma unroll
      for (int j = 0; j < 4; j++) {
        int col = bn + wn + j * 16 + lrow;
#pragma unroll
        for (int r = 0; r < 4; r++)
          C[(size_t)(row + r) * ldc + col] = f2b(acc[i][j][r]);
      }
    }
  } else if constexpr (MODE == 2) {
    float* C = (float*)Cout;
#pragma unroll
    for (int i = 0; i < 4; i++) {
      int row = bm + wm + i * 16 + quad * 4;
#pragma unroll
      for (int j = 0; j < 4; j++) {
        int col = bn + wn + j * 16 + lrow;
        float bias = wg[col];
#pragma unroll
        for (int r = 0; r < 4; r++)
          C[(size_t)(row + r) * ldc + col] = acc[i][j][r] + bias;
      }
    }
  } else {  // MODE 1
    float* C = (float*)Cout;
#pragma unroll
    for (int i = 0; i < 4; i++) {
#pragma unroll
      for (int r = 0; r < 4; r++) {
        int m = bm + wm + i * 16 + quad * 4 + r;
        int b = m >> 4, t0 = m & 15;
        size_t orow = (size_t)t0 * 512 + b;
#pragma unroll
        for (int j = 0; j < 4; j++) {
          int col = bn + wn + j * 16 + lrow;
          C[orow * 2048 + col] = acc[i][j][r] + wg[(size_t)b * 2048 + col];
        }
      }
    }
  }
}

// -------------------------------------------------------------------------
// Persistent 16-step LSTM kernel (cooperative, 256 WGs x 256 threads).
// WG (rb,cb): batch rows rb*32..+32, h cols cb*32..+32. Wave = gate.
// Coherence design (NO agent fences -- they are cache-wide wbl2/inv on
// gfx950 and were the round-1 disaster):
//  - h writes: relaxed agent-scope 8B atomic stores (write-through past the
//    non-coherent XCD L2 to the LLC).
//  - h reads: PLAIN cached loads from a 17-slot ring. 16 steps/dispatch ->
//    every slot read was written exactly once this dispatch at a fresh
//    address; no cache can hold a stale copy.
//  - barrier: __syncthreads() (drains vmcnt -> sc1 stores at LLC) + relaxed
//    agent atomic add + relaxed poll. No cache-maintenance ops.
//  - bid mapping rb=((bid&7)<<1)|((bid>>3)&1): all 16 WGs of a batch-group
//    share bid%8 (same XCD under round-robin) -> fresh h lines pulled from
//    LLC once per XCD, served 16x from L2. Correctness doesn't depend on it.
// Whh B-fragments pinned in VGPRs (empty asm) across all 16 steps; c-state
// lives in registers for the whole dispatch.
__global__ __launch_bounds__(256, 1)
void lstm16_kernel(const uint16_t* __restrict__ Whhb,   // [2048,512] bf16
                   const float* __restrict__ xg,        // [16,512,2048] f32
                   uint16_t* __restrict__ hring,        // [17,512,512] bf16
                   float* __restrict__ cst,             // [512,512] f32
                   void* __restrict__ out,
                   int tbase,
                   const int* __restrict__ flagp,
                   unsigned int* __restrict__ bar) {
  __shared__ __align__(16) uint16_t Hs[32 * 512];  // 32 KB, XOR-swizzled rows
  __shared__ float Gs[4][32][33];                  // 16.9 KB gate staging

  const int tid = threadIdx.x;
  const int bid = blockIdx.x;
  const int rb = ((bid & 7) << 1) | ((bid >> 3) & 1);  // 0..15
  const int cb = bid >> 4;                             // 0..15
  const int g = tid >> 6;                              // wave = gate (i,f,g,o)
  const int lane = tid & 63;
  const int lrow = lane & 15, quad = lane >> 4;
  const int fl = *flagp;

  // ---- Whh B-fragments for this wave's 32 gate-rows, all K, pinned ----
  u32x4 breg[2][16];
  {
    const uint16_t* wb = Whhb + ((size_t)(g * 512 + cb * 32 + lrow) * 512) + quad * 8;
#pragma unroll
    for (int j = 0; j < 2; j++)
#pragma unroll
      for (int kk = 0; kk < 16; kk++) {
        breg[j][kk] = *reinterpret_cast<const u32x4*>(wb + (size_t)j * 16 * 512 + kk * 32);
        asm volatile("" : "+v"(breg[j][kk]));  // force resident; block remat
      }
  }

  // ---- epilogue mapping: thread -> (row, 4 consecutive h cols) ----
  const int erow = tid >> 3;        // 0..31
  const int ecol = (tid & 7) * 4;   // 0..28
  const int gb = rb * 32 + erow;    // global batch row
  const int gh = cb * 32 + ecol;    // global h col
  f32x4 creg = *reinterpret_cast<const f32x4*>(cst + (size_t)gb * 512 + gh);

  const int sc16 = (tid & 7) * 16;  // staging byte-col base
  const int ssw = (erow & 7) << 4;  // staging row swizzle
  unsigned int* cnt = bar + rb * 64;  // 256 B apart per group

#pragma unroll 1
  for (int s = 0; s < 16; s++) {
    const int t = tbase + s;
    const uint16_t* hin = hring + (size_t)((t + 16) % 17) * 262144;  // h(t-1)
    uint16_t* hout = hring + (size_t)(t % 17) * 262144;              // h(t)

    // xg prefetch (independent of h; latency hidden under stage+GEMM)
    const float* xr = xg + ((size_t)s * 512 + gb) * 2048 + gh;
    f32x4 x0 = *reinterpret_cast<const f32x4*>(xr);
    f32x4 x1 = *reinterpret_cast<const f32x4*>(xr + 512);
    f32x4 x2 = *reinterpret_cast<const f32x4*>(xr + 1024);
    f32x4 x3 = *reinterpret_cast<const f32x4*>(xr + 1536);

    // stage h(t-1)[rb rows, all 512 cols] into LDS, swizzled (plain loads)
    {
      const char* hsrc = (const char*)(hin + (size_t)gb * 512);
      char* hdst = (char*)Hs + erow * 1024;
#pragma unroll
      for (int it = 0; it < 8; it++) {
        int bc = sc16 + it * 128;
        *reinterpret_cast<uint4*>(hdst + (bc ^ ssw)) =
            *reinterpret_cast<const uint4*>(hsrc + bc);
      }
    }
    __syncthreads();

    // GEMM: gate-g preacts [32 x 32], K=512 from registers(B) x LDS(A)
    f32x4 acc[2][2] = {};
#pragma unroll
    for (int kk = 0; kk < 16; kk++) {
      bf16x8 af[2];
#pragma unroll
      for (int i = 0; i < 2; i++) {
        int r = i * 16 + lrow;
        int bc = kk * 64 + quad * 16;
        af[i] = *reinterpret_cast<const bf16x8*>(
            (const char*)Hs + r * 1024 + (bc ^ ((r & 7) << 4)));
      }
#pragma unroll
      for (int i = 0; i < 2; i++)
#pragma unroll
        for (int j = 0; j < 2; j++)
          acc[i][j] = __builtin_amdgcn_mfma_f32_16x16x32_bf16(
              af[i], __builtin_bit_cast(bf16x8, breg[j][kk]), acc[i][j], 0, 0, 0);
    }

#pragma unroll
    for (int i = 0; i < 2; i++)
#pragma unroll
      for (int j = 0; j < 2; j++)
#pragma unroll
        for (int r = 0; r < 4; r++)
          Gs[g][i * 16 + quad * 4 + r][j * 16 + lrow] = acc[i][j][r];
    __syncthreads();

    // epilogue: 4 outputs/thread, c in registers
    float hnv[4];
#pragma unroll
    for (int e = 0; e < 4; e++) {
      float p_i = Gs[0][erow][ecol + e] + x0[e];
      float p_f = Gs[1][erow][ecol + e] + x1[e];
      float p_g = Gs[2][erow][ecol + e] + x2[e];
      float p_o = Gs[3][erow][ecol + e] + x3[e];
      float si = fsig(p_i);
      float sf = fsig(p_f);
      float so = fsig(p_o);
      float tg = ftanh(p_g);
      float cn = sf * creg[e] + si * tg;
      creg[e] = cn;
      hnv[e] = so * ftanh(cn);
    }
    uint2 hp;
    hp.x = (uint32_t)f2b(hnv[0]) | ((uint32_t)f2b(hnv[1]) << 16);
    hp.y = (uint32_t)f2b(hnv[2]) | ((uint32_t)f2b(hnv[3]) << 16);
    // h store: write-through to LLC (agent-scope relaxed), no fence
    u64 hv = (u64)hp.x | ((u64)hp.y << 32);
    __hip_atomic_store((u64*)(hout + (size_t)gb * 512 + gh), hv,
                       __ATOMIC_RELAXED, __HIP_MEMORY_SCOPE_AGENT);
    size_t oi = (size_t)gb * (80 * 512) + (size_t)t * 512 + gh;
    if (fl) {
      *reinterpret_cast<uint2*>((uint16_t*)out + oi) = hp;
    } else {
      float4 ov = make_float4(hnv[0], hnv[1], hnv[2], hnv[3]);
      *reinterpret_cast<float4*>((float*)out + oi) = ov;
    }

    // group barrier: syncthreads drains vmcnt (stores at LLC), then one
    // relaxed agent atomic arrive + poll. No cache-maintenance ops.
    __syncthreads();
    if (tid == 0) {
      __hip_atomic_fetch_add(cnt, 1u, __ATOMIC_RELAXED, __HIP_MEMORY_SCOPE_AGENT);
      if (s != 15) {  // last step: arrive only (next chunk is stream-ordered)
        unsigned tgt = (unsigned)(t + 1) * 16u;
        while (__hip_atomic_load(cnt, __ATOMIC_RELAXED, __HIP_MEMORY_SCOPE_AGENT) < tgt)
          __builtin_amdgcn_s_sleep(1);
      }
    }
    __syncthreads();
  }

  *reinterpret_cast<f32x4*>(cst + (size_t)gb * 512 + gh) = creg;
}

// -------------------------------------------------------------------------
extern "C" void kernel_launch(void* const* d_in, const int* in_sizes, int n_in,
                              void* d_out, int out_size, void* d_ws, size_t ws_size,
                              hipStream_t stream) {
  const void* enc   = d_in[0];            // [512,80,1024]
  const int*  ids   = (const int*)d_in[1];
  const void* Wproj = d_in[2];            // [1024,512]
  const void* bproj = d_in[3];
  const void* embed = d_in[4];            // [10000,512]
  const void* Wih   = d_in[5];            // [2048,1024]
  const void* Whh   = d_in[6];            // [2048,512]
  const void* bih   = d_in[7];
  const void* bhh   = d_in[8];

  uint8_t* w = (uint8_t*)d_ws;
  int*      flag   = (int*)w;                    // 16 KB reserved
  unsigned int* bar = (unsigned int*)(w + 8192); // 4 KB barrier counters
  float*    bias2  = (float*)(w + 16384);        // 8 KB
  float*    wgates = (float*)(w + 32768);        // [512,2048] f32, 4 MB
  uint16_t* combT  = (uint16_t*)(w + 4227072);   // [2048,1024] bf16, 4 MB
  uint16_t* Wihb   = (uint16_t*)(w + 8421376);   // [2048,1024] bf16, 4 MB
  uint16_t* Whhb   = (uint16_t*)(w + 12615680);  // [2048,512] bf16, 2 MB
  uint16_t* Wprojb = (uint16_t*)(w + 14712832);  // [1024,512] bf16, 1 MB
  uint16_t* word   = (uint16_t*)(w + 15761408);  // [512,512] bf16, 512 KB
  float*    cst    = (float*)(w + 17334272);     // [512,512] f32, 1 MB
  float*    xgbuf  = (float*)(w + 18382848);     // [16,512,2048] f32, 64 MB
  uint16_t* hring  = (uint16_t*)(w + 85491712);  // [17,512,512] bf16, 8.9 MB
  uint16_t* encb   = (uint16_t*)(w + 94404608);  // [8192,1024] bf16, 16.8 MB

  detect_kernel<<<1, 256, 0, stream>>>((const uint32_t*)Wproj, flag);
  convert_kernel<<<1024, 256, 0, stream>>>(Wih, Wihb, flag);     // 2M elems
  convert_kernel<<<512, 256, 0, stream>>>(Whh, Whhb, flag);      // 1M
  convert_kernel<<<256, 256, 0, stream>>>(Wproj, Wprojb, flag);  // 512K
  word_kernel<<<128, 256, 0, stream>>>(ids, embed, word, flag);
  bias2_kernel<<<512, 256, 0, stream>>>(bih, bhh, bproj, Wihb, bias2, flag);

  // combT[j,d] = sum_f W_ih[j,f] * W_proj[d,f]   (M=2048,N=1024,K=512)
  gemm_bt<0><<<dim3(8, 16), 256, 0, stream>>>(Wihb, 1024, Wprojb, 512,
                                              combT, 1024, 512, nullptr);
  // wgates[b,j] = sum_w word[b,w]*W_ih[j,512+w] + bias2[j]  (M=512,N=2048,K=512)
  gemm_bt<2><<<dim3(16, 4), 256, 0, stream>>>(word, 512, Wihb + 512, 1024,
                                              wgates, 2048, 512, bias2);

  (void)hipMemsetAsync(hring + (size_t)16 * 262144, 0, 524288, stream);  // h(-1)=0
  (void)hipMemsetAsync(cst, 0, 512 * 512 * 4, stream);
  (void)hipMemsetAsync(bar, 0, 4096, stream);

  const uint16_t* Whhb_a = Whhb;
  const float* xg_a = xgbuf;
  uint16_t* hring_a = hring;
  float* cst_a = cst;
  void* out_a = d_out;
  const int* flag_a = flag;
  unsigned int* bar_a = bar;

  for (int c = 0; c < 5; c++) {
    // encb[m,d] = bf16(enc[b, c*16+t0, d]),  m = b*16+t0
    convA_kernel<<<4096, 256, 0, stream>>>(enc, encb, flag, c * 16);
    // xgbuf[t0,b,j] = sum_d encb[b*16+t0,d]*combT[j,d] + wgates[b,j]
    gemm_bt<1><<<dim3(16, 64), 256, 0, stream>>>(encb, 1024, combT, 1024,
                                                 xgbuf, 2048, 1024, wgates);
    int tbase = c * 16;
    void* kargs[] = {(void*)&Whhb_a, (void*)&xg_a, (void*)&hring_a,
                     (void*)&cst_a, (void*)&out_a, (void*)&tbase, (void*)&flag_a,
                     (void*)&bar_a};
    (void)hipLaunchCooperativeKernel(lstm16_kernel, dim3(256), dim3(256), kargs,
                                     0u, stream);
  }
}